// Round 23
// baseline (54.481 us; speedup 1.0000x reference)
//
#include <hip/hip_runtime.h>

#define B_ 64
#define T_ 1000
#define C_ 128
#define L_ 100
#define BLANK 127     // C-1
#define LN2F 0.69314718055994530942f
#define NPROD 4
#define SLOTSZ 8192   // one composite slot: 8 coef-pairs x (64 lanes x 16B)
#define BUFSZ (8 * SLOTSZ)   // 8 slots (16 steps) per phase; 64KB

__device__ __forceinline__ float flog2(float x) { return __builtin_amdgcn_logf(x); }
__device__ __forceinline__ float frcp(float x)  { return __builtin_amdgcn_rcpf(x); }

#define DPP_ROW_SHR1   0x111
#define DPP_ROW_SHR2   0x112
#define DPP_ROW_SHR4   0x114
#define DPP_ROW_SHR8   0x118
#define DPP_WAVE_SHR1  0x138   // lane i <- lane i-1 (validated R8)
#define DPP_WAVE_SHL1  0x130   // lane i <- lane i+1 (validated R15/R16)

template <int CTRL>
__device__ __forceinline__ int dpp_mov(int src) {
    return __builtin_amdgcn_update_dpp(0, src, CTRL, 0xF, 0xF, false);
}

// R22b: 2-step COMPOSITION (compile-fixed). Producers precompute the 16
// f64 coefficients of the composed bandwidth-4 linear map; the consumer
// composite = 8 ds_read_b128 + 16 f64 FMA (tree depth 3) + DPP, covering
// TWO steps -> halves issue count and the serial f64 chain. Odd tails:
// single-step K rows (reproduce validated STEPQ/STEPB exactly).
__global__ __launch_bounds__(320) void ctc_split_kernel(
    const int* __restrict__ y_true, const float* __restrict__ y_pred,
    const int* __restrict__ in_len, const int* __restrict__ lab_len,
    double* __restrict__ AVf, double* __restrict__ AVb,
    double* __restrict__ Ls, int* __restrict__ Es)
{
    const int bb    = blockIdx.x & 63;
    const bool isB  = blockIdx.x >= 64;
    const int tid   = threadIdx.x;
    const int l     = tid & 63;
    const int wv    = tid >> 6;          // 0 = consumer, 1..4 = producers

    __shared__ __align__(16) char ldsb[2 * BUFSZ];   // 128 KiB
    __shared__ float lgs[2][NPROD];

    const int* yb = y_true + bb * L_;
    const int k1 = min(2 * l, L_ - 1);
    const int k3 = min(2 * l + 1, L_ - 1);
    const int e1 = yb[k1];
    const int e3 = yb[k3];
    const float m1f  = (k1 == 0 || e1 != yb[k1 - 1]) ? 1.f : 0.f;
    const float m3f  = (e3 != yb[k3 - 1]) ? 1.f : 0.f;
    const int kp  = min(max(2 * l - 1, 1), L_ - 1);
    const float mpf  = (yb[kp] != yb[kp - 1]) ? 1.f : 0.f;       // lane0: dead
    const int k1n = min(2 * l + 2, L_ - 1);
    const float m1nf = (yb[k1n] != yb[k1n - 1]) ? 1.f : 0.f;
    const int k3n = min(2 * l + 3, L_ - 1);
    const float m3nf = (yb[k3n] != yb[k3n - 1]) ? 1.f : 0.f;
    const int ep  = yb[min(max(2 * l - 1, 0), L_ - 1)];   // position 4l-1
    const int e1n = yb[k1n];                               // position 4l+5
    const int e3n = yb[k3n];                               // position 4l+7

    const int Teff = min(T_, in_len[bb]);
    const int N    = Teff - 1;
    const int Hf   = (N + 1) >> 1;
    const int Hb   = N - Hf;
    const int steps_total = isB ? Hb : Hf;
    const int ST   = (steps_total + 1) >> 1;   // composite slots
    const int P    = (ST + 7) >> 3;            // phases (8 slots = 16 steps)
    const float* rowb = y_pred + (size_t)bb * T_ * C_;

    double a0 = 0.0, a1 = 0.0, a2 = 0.0, a3 = 0.0;
    double Lsum = 0.0;
    int E = 0;

#define WRP(p_, X_, Y_) { *(double2*)(sbase + (p_) * 1024 + 16 * l) = \
        make_double2((double)(X_), (double)(Y_)); }

    // ---- producer: emit one composite slot's 16 coefficients ----
    auto fill_slot = [&](int ss, float& lgacc) {
        char* sbase = ldsb + ((ss >> 3) & 1) * BUFSZ + (ss & 7) * SLOTSZ;
        if (!isB) {
            const int t1   = 2 * ss + 1;
            const bool full = (2 * ss + 2 <= Hf);
            const int t2   = full ? t1 + 1 : t1;
            const float* r1 = rowb + (size_t)t1 * C_;
            const float* r2 = rowb + (size_t)t2 * C_;
            float p1a = r1[e1], p1b = r1[e3], p1p = r1[ep], b1v = r1[BLANK];
            float p2a = r2[e1], p2b = r2[e3], b2v = r2[BLANK];
            __builtin_amdgcn_sched_barrier(0);
            float rc1 = frcp(b1v + 1e-7f), rc2 = frcp(b2v + 1e-7f);
            float qa = (p1a + 1e-7f) * rc1, qb = (p1b + 1e-7f) * rc1,
                  qp = (p1p + 1e-7f) * rc1;
            float ra = (p2a + 1e-7f) * rc2, rb = (p2b + 1e-7f) * rc2;
            float K01,K02,K03,K11,K12,K13,K14,K15,K21,K22,K23,K31,K32,K33,K34,K35;
            if (full) {
                K01 = 1.f + qp;  K02 = qp;  K03 = mpf * qp;
                K11 = ra * qa;   K12 = ra * (qa + 1.f);
                K13 = ra * (m1f * (qa + qp) + 1.f);
                K14 = ra * m1f * qp;  K15 = K14 * mpf;
                K21 = 1.f + qa;  K22 = qa;  K23 = m1f * qa;
                K31 = rb * qb;   K32 = rb * (qb + 1.f);
                K33 = rb * (m3f * (qb + qa) + 1.f);
                K34 = rb * m3f * qa;  K35 = K34 * m1f;
            } else {   // single step (== validated STEPQ)
                K01 = 1.f; K02 = 0.f; K03 = 0.f;
                K11 = qa;  K12 = qa;  K13 = m1f * qa; K14 = 0.f; K15 = 0.f;
                K21 = 1.f; K22 = 0.f; K23 = 0.f;
                K31 = qb;  K32 = qb;  K33 = m3f * qb; K34 = 0.f; K35 = 0.f;
            }
            WRP(0,K01,K02); WRP(1,K03,K11); WRP(2,K12,K13); WRP(3,K14,K15);
            WRP(4,K21,K22); WRP(5,K23,K31); WRP(6,K32,K33); WRP(7,K34,K35);
            lgacc += flog2(b1v + 1e-7f) + (full ? flog2(b2v + 1e-7f) : 0.f);
        } else {
            const int fR   = N - 2 * ss;         // applied FIRST (inner)
            const bool full = (2 * ss + 2 <= Hb);
            const int fQ   = full ? fR - 1 : fR; // applied second (outer)
            const float* rQ = rowb + (size_t)fQ * C_;
            const float* rR = rowb + (size_t)fR * C_;
            float gqa = rQ[e1], gqb = rQ[e3], gqan = rQ[e1n], bQ = rQ[BLANK];
            float gra = rR[e1], grb = rR[e3], gran = rR[e1n], grbn = rR[e3n],
                  bR  = rR[BLANK];
            __builtin_amdgcn_sched_barrier(0);
            float rcQ = frcp(bQ + 1e-7f), rcR = frcp(bR + 1e-7f);
            float qa1  = (gqa  + 1e-7f) * rcQ, qb1  = (gqb  + 1e-7f) * rcQ,
                  qa1n = (gqan + 1e-7f) * rcQ;
            float ra2  = (gra  + 1e-7f) * rcR, rb2  = (grb  + 1e-7f) * rcR,
                  ra2n = (gran + 1e-7f) * rcR, rb2n = (grbn + 1e-7f) * rcR;
            float T01,T02,T03,T11,T12,T13,T14,T15,T21,T22,T23,T31,T32,T33,T34,T35;
            if (full) {
                T01 = ra2 * (qa1 + 1.f); T02 = qa1; T03 = rb2 * m3f * qa1;
                T11 = ra2 * qa1; T12 = 1.f + qa1;
                T13 = rb2 * (m3f * (qb1 + qa1) + 1.f);
                T14 = m3f * qb1; T15 = ra2n * m1nf * T14;
                T21 = rb2 * (qb1 + 1.f); T22 = qb1; T23 = ra2n * m1nf * qb1;
                T31 = rb2 * qb1; T32 = 1.f + qb1;
                T33 = ra2n * (m1nf * (qa1n + qb1) + 1.f);
                T34 = m1nf * qa1n; T35 = rb2n * m3nf * T34;
            } else {   // single step (== validated STEPB), frame fR
                T01 = ra2; T02 = 0.f; T03 = 0.f;
                T11 = ra2; T12 = 1.f; T13 = m3f * rb2; T14 = 0.f; T15 = 0.f;
                T21 = rb2; T22 = 0.f; T23 = 0.f;
                T31 = rb2; T32 = 1.f; T33 = m1nf * ra2n; T34 = 0.f; T35 = 0.f;
            }
            WRP(0,T01,T02); WRP(1,T03,T11); WRP(2,T12,T13); WRP(3,T14,T15);
            WRP(4,T21,T22); WRP(5,T23,T31); WRP(6,T32,T33); WRP(7,T34,T35);
            lgacc += flog2(bR + 1e-7f) + (full ? flog2(bQ + 1e-7f) : 0.f);
        }
    };

    auto fill_phase = [&](int phf) {
        float lg_ = 0.f;
        const int s0 = phf * 8 + (wv - 1) * 2;
        if (s0     < ST) fill_slot(s0,     lg_);
        if (s0 + 1 < ST) fill_slot(s0 + 1, lg_);
        if (l == 0) lgs[phf & 1][wv - 1] = lg_;
    };

#define DECLP(BK) double2 BK##0,BK##1,BK##2,BK##3,BK##4,BK##5,BK##6,BK##7
#define LDP(BK, k_) { const char* sb_ = base_ + (k_) * SLOTSZ + 16 * l; \
    BK##0 = *(const double2*)(sb_);        BK##1 = *(const double2*)(sb_ + 1024); \
    BK##2 = *(const double2*)(sb_ + 2048); BK##3 = *(const double2*)(sb_ + 3072); \
    BK##4 = *(const double2*)(sb_ + 4096); BK##5 = *(const double2*)(sb_ + 5120); \
    BK##6 = *(const double2*)(sb_ + 6144); BK##7 = *(const double2*)(sb_ + 7168); }

#define APPLYF(BK) { \
    int l1_ = dpp_mov<DPP_WAVE_SHR1>(__double2loint(a1)), h1_ = dpp_mov<DPP_WAVE_SHR1>(__double2hiint(a1)); \
    int l2_ = dpp_mov<DPP_WAVE_SHR1>(__double2loint(a2)), h2_ = dpp_mov<DPP_WAVE_SHR1>(__double2hiint(a2)); \
    int l3_ = dpp_mov<DPP_WAVE_SHR1>(__double2loint(a3)), h3_ = dpp_mov<DPP_WAVE_SHR1>(__double2hiint(a3)); \
    double pa1_ = __hiloint2double(h1_, l1_), pa2_ = __hiloint2double(h2_, l2_), \
           pa3_ = __hiloint2double(h3_, l3_); \
    double c0_ = fma((BK##0).x, pa3_, a0); c0_ = fma((BK##0).y, pa2_, c0_); c0_ = fma((BK##1).x, pa1_, c0_); \
    double c1_ = (BK##1).y * a1; c1_ = fma((BK##2).x, a0, c1_); c1_ = fma((BK##2).y, pa3_, c1_); \
    c1_ = fma((BK##3).x, pa2_, c1_); c1_ = fma((BK##3).y, pa1_, c1_); \
    double c2_ = fma((BK##4).x, a1, a2); c2_ = fma((BK##4).y, a0, c2_); c2_ = fma((BK##5).x, pa3_, c2_); \
    double c3_ = (BK##5).y * a3; c3_ = fma((BK##6).x, a2, c3_); c3_ = fma((BK##6).y, a1, c3_); \
    c3_ = fma((BK##7).x, a0, c3_); c3_ = fma((BK##7).y, pa3_, c3_); \
    a0 = c0_; a1 = c1_; a2 = c2_; a3 = c3_; }

#define APPLYB(BK) { \
    int l0_ = dpp_mov<DPP_WAVE_SHL1>(__double2loint(a0)), h0_ = dpp_mov<DPP_WAVE_SHL1>(__double2hiint(a0)); \
    int l1_ = dpp_mov<DPP_WAVE_SHL1>(__double2loint(a1)), h1_ = dpp_mov<DPP_WAVE_SHL1>(__double2hiint(a1)); \
    int l2_ = dpp_mov<DPP_WAVE_SHL1>(__double2loint(a2)), h2_ = dpp_mov<DPP_WAVE_SHL1>(__double2hiint(a2)); \
    int l3_ = dpp_mov<DPP_WAVE_SHL1>(__double2loint(a3)), h3_ = dpp_mov<DPP_WAVE_SHL1>(__double2hiint(a3)); \
    double nb0_ = __hiloint2double(h0_, l0_), nb1_ = __hiloint2double(h1_, l1_), \
           nb2_ = __hiloint2double(h2_, l2_), nb3_ = __hiloint2double(h3_, l3_); \
    double t0_ = fma((BK##0).x, a1, a0); t0_ = fma((BK##0).y, a2, t0_); t0_ = fma((BK##1).x, a3, t0_); \
    double t1_ = (BK##1).y * a1; t1_ = fma((BK##2).x, a2, t1_); t1_ = fma((BK##2).y, a3, t1_); \
    t1_ = fma((BK##3).x, nb0_, t1_); t1_ = fma((BK##3).y, nb1_, t1_); \
    double t2_ = fma((BK##4).x, a3, a2); t2_ = fma((BK##4).y, nb0_, t2_); t2_ = fma((BK##5).x, nb1_, t2_); \
    double t3_ = (BK##5).y * a3; t3_ = fma((BK##6).x, nb0_, t3_); t3_ = fma((BK##6).y, nb1_, t3_); \
    t3_ = fma((BK##7).x, nb2_, t3_); t3_ = fma((BK##7).y, nb3_, t3_); \
    a0 = t0_; a1 = t1_; a2 = t2_; a3 = t3_; }

#define DPPMAX(u_, ctrl_) { unsigned t_ = (unsigned)dpp_mov<ctrl_>((int)(u_)); \
    u_ = max(u_, t_); }
#define RESCALE() { \
    unsigned u_ = max(max((unsigned)__double2hiint(a0), (unsigned)__double2hiint(a1)), \
                      max((unsigned)__double2hiint(a2), (unsigned)__double2hiint(a3))); \
    DPPMAX(u_, DPP_ROW_SHR1); \
    DPPMAX(u_, DPP_ROW_SHR2); \
    DPPMAX(u_, DPP_ROW_SHR4); \
    DPPMAX(u_, DPP_ROW_SHR8); \
    unsigned g_ = max(max((unsigned)__builtin_amdgcn_readlane((int)u_, 15), \
                          (unsigned)__builtin_amdgcn_readlane((int)u_, 31)), \
                      max((unsigned)__builtin_amdgcn_readlane((int)u_, 47), \
                          (unsigned)__builtin_amdgcn_readlane((int)u_, 63))); \
    int kk_ = (int)(g_ >> 20); \
    if (kk_ > 0) { \
        double f_ = __hiloint2double((2046 - kk_) << 20, 0); \
        a0 *= f_; a1 *= f_; a2 *= f_; a3 *= f_; \
        E += kk_ - 1023; } }

    if (wv >= 1) {
        fill_phase(0);
    } else if (!isB) {
        __builtin_amdgcn_s_setprio(1);
        float pb0_ = rowb[BLANK] + 1e-7f;
        float p10_ = rowb[e1]    + 1e-7f;
        a0 = (l == 0) ? 1.0 : 0.0;
        a1 = (l == 0) ? (double)(p10_ / pb0_) : 0.0;
        Lsum = (double)flog2(pb0_);
    } else {
        __builtin_amdgcn_s_setprio(1);
        const int llb = lab_len[bb];
        const int pa = 2 * llb, pq = 2 * llb - 1;
        a0 = (4 * l     == pa) ? 1.0 : 0.0;
        a1 = (4 * l + 1 == pq) ? 1.0 : 0.0;
        a2 = (4 * l + 2 == pa) ? 1.0 : 0.0;
        a3 = (4 * l + 3 == pq) ? 1.0 : 0.0;
    }
    __syncthreads();

    for (int ph = 0; ph < P; ++ph) {
        if (wv >= 1) {
            if (ph + 1 < P) fill_phase(ph + 1);
        } else {
            const char* base_ = ldsb + (ph & 1) * BUFSZ;
            const int sp = min(8, ST - ph * 8);
            if (sp == 8) {
                DECLP(A); DECLP(B);
                LDP(A, 0); LDP(B, 1);
                if (!isB) {
                    APPLYF(A); LDP(A, 2); APPLYF(B); LDP(B, 3);
                    APPLYF(A); LDP(A, 4); APPLYF(B); LDP(B, 5);
                    APPLYF(A); LDP(A, 6); APPLYF(B); LDP(B, 7);
                    APPLYF(A); APPLYF(B);
                } else {
                    APPLYB(A); LDP(A, 2); APPLYB(B); LDP(B, 3);
                    APPLYB(A); LDP(A, 4); APPLYB(B); LDP(B, 5);
                    APPLYB(A); LDP(A, 6); APPLYB(B); LDP(B, 7);
                    APPLYB(A); APPLYB(B);
                }
                RESCALE();
            } else {
                for (int k_ = 0; k_ < sp; ++k_) {
                    DECLP(Tt);
                    LDP(Tt, k_);
                    if (!isB) { APPLYF(Tt); } else { APPLYB(Tt); }
                }
                RESCALE();
            }
            float lg_ = 0.f;
            #pragma unroll
            for (int w_ = 0; w_ < NPROD; ++w_) lg_ += lgs[ph & 1][w_];
            Lsum += (double)lg_;
        }
        __syncthreads();
    }

    if (wv == 0) {
        double* AV = (isB ? AVb : AVf) + bb * 256;
        AV[4 * l + 0] = a0; AV[4 * l + 1] = a1;
        AV[4 * l + 2] = a2; AV[4 * l + 3] = a3;
        if (l == 0) {
            Ls[bb * 2 + (isB ? 1 : 0)] = Lsum;
            Es[bb * 2 + (isB ? 1 : 0)] = E;
        }
    }
}

__global__ __launch_bounds__(64) void ctc_combine_kernel(
    const double* __restrict__ AVf, const double* __restrict__ AVb,
    const double* __restrict__ Ls, const int* __restrict__ Es,
    float* __restrict__ out)
{
    const int b = blockIdx.x;
    const int l = threadIdx.x;
    const double* f = AVf + b * 256;
    const double* g = AVb + b * 256;
    double d = f[4*l+0]*g[4*l+0] + f[4*l+1]*g[4*l+1]
             + f[4*l+2]*g[4*l+2] + f[4*l+3]*g[4*l+3];
    d += __shfl_xor(d, 1);  d += __shfl_xor(d, 2);  d += __shfl_xor(d, 4);
    d += __shfl_xor(d, 8);  d += __shfl_xor(d, 16); d += __shfl_xor(d, 32);
    if (l == 0) {
        double Ltot = Ls[b * 2] + Ls[b * 2 + 1];
        int    Etot = Es[b * 2] + Es[b * 2 + 1];
        int hi = __double2hiint(d), lo = __double2loint(d);
        int ke = (hi >> 20) & 0x7FF;
        double mant = __hiloint2double((hi & 0x000FFFFF) | (1023 << 20), lo);
        float r = flog2((float)mant) + (float)(ke - 1023 + Etot) + (float)Ltot;
        out[b] = -r * LN2F;
    }
}

extern "C" void kernel_launch(void* const* d_in, const int* in_sizes, int n_in,
                              void* d_out, int out_size, void* d_ws, size_t ws_size,
                              hipStream_t stream) {
    const int*   y_true  = (const int*)d_in[0];
    const float* y_pred  = (const float*)d_in[1];
    const int*   in_len  = (const int*)d_in[2];
    const int*   lab_len = (const int*)d_in[3];
    float*       out     = (float*)d_out;

    double* AVf = (double*)d_ws;                 // [64][256]
    double* AVb = AVf + 64 * 256;                // [64][256]
    double* Ls  = AVb + 64 * 256;                // [64][2]
    int*    Es  = (int*)(Ls + 128);              // [64][2]

    ctc_split_kernel<<<128, 320, 0, stream>>>(y_true, y_pred, in_len, lab_len,
                                              AVf, AVb, Ls, Es);
    ctc_combine_kernel<<<64, 64, 0, stream>>>(AVf, AVb, Ls, Es, out);
}